// Round 4
// baseline (866.748 us; speedup 1.0000x reference)
//
#include <hip/hip_runtime.h>
#include <hip/hip_bf16.h>
#include <stdint.h>

#define DEV __device__ __forceinline__

// Problem constants
constexpr int B_ = 8, N_ = 131072, S_ = 1024, C_ = 32;
constexpr float INV_R1 = 2.5f;   // 1/RADIUS (0.4)
constexpr float INV_R2 = 1.25f;  // 1/RADIUS_POST (0.8)

// Scaled-weight region offsets (in floats) inside ws
constexpr int OW1AS = 0;        // w1a*s1a      [38][32]
constexpr int OW1BS = 1216;     // w1b*s1b      [32][64]
constexpr int OT1B  = 3264;     // t1b          [64]
constexpr int OW2S  = 3328;     // w2*s2        [70][64]
constexpr int OT2   = 7808;     // t2           [64]
constexpr int OW3AS = 7872;     // w3a*s3a      [64][256]
constexpr int OT3A  = 24256;    // t3a          [256]
constexpr int OW3BS = 24512;    // w3b*s3b     [256][64]
constexpr int OT3B  = 40896;    // t3b          [64]   -> 40960 floats total

// ws byte offsets
constexpr size_t WS_CTR  = 163840;                          // ctr records [8192][104] f32
constexpr size_t WS_NF   = WS_CTR  + (size_t)8192*104*4;    // new_features [8192][64] f32
constexpr size_t WS_P2   = WS_NF   + (size_t)524288*4;      // stage2 point-precompute [8192][64] f32
constexpr size_t WS_HOUT = WS_P2   + (size_t)524288*4;      // final features [8192][64] f32
constexpr size_t WS_PREC = WS_HOUT + (size_t)524288*4;      // point records P [B*N][32] bf16

DEV float bfu(uint16_t u){ return __uint_as_float(((uint32_t)u) << 16); }

// ---------------------------------------------------------------- k_weights
__global__ void k_weights(
    const float* __restrict__ w1a, const float* __restrict__ s1a,
    const float* __restrict__ w1b, const float* __restrict__ s1b,
    const float* __restrict__ t1b,
    const float* __restrict__ w2,  const float* __restrict__ s2,
    const float* __restrict__ t2,
    const float* __restrict__ w3a, const float* __restrict__ s3a,
    const float* __restrict__ t3a,
    const float* __restrict__ w3b, const float* __restrict__ s3b,
    const float* __restrict__ t3b,
    float* __restrict__ wsw)
{
  int t = blockIdx.x*256 + threadIdx.x;
  int nth = gridDim.x*256;
  for (int i=t;i<38*32;i+=nth)  wsw[OW1AS+i] = w1a[i]*s1a[i&31];
  for (int i=t;i<32*64;i+=nth)  wsw[OW1BS+i] = w1b[i]*s1b[i&63];
  for (int i=t;i<64;i+=nth)     wsw[OT1B+i]  = t1b[i];
  for (int i=t;i<70*64;i+=nth)  wsw[OW2S+i]  = w2[i]*s2[i&63];
  for (int i=t;i<64;i+=nth)     wsw[OT2+i]   = t2[i];
  for (int i=t;i<64*256;i+=nth) wsw[OW3AS+i] = w3a[i]*s3a[i&255];
  for (int i=t;i<256;i+=nth)    wsw[OT3A+i]  = t3a[i];
  for (int i=t;i<256*64;i+=nth) wsw[OW3BS+i] = w3b[i]*s3b[i&63];
  for (int i=t;i<64;i+=nth)     wsw[OT3B+i]  = t3b[i];
}

// ---------------------------------------------------------------- k_points
// P[n] = (xyz/R)@W1a[0:3] + feats[n]@W1a[6:38], stored bf16.
// 2 points/thread: each wave-uniform weight s_load feeds 2 FMAs; feats as float2.
__global__ __launch_bounds__(256) void k_points(
    const float* __restrict__ locs,
    const float* __restrict__ feats,
    const float* __restrict__ wsw,
    __hip_bfloat16* __restrict__ prec)
{
  size_t t = (size_t)blockIdx.x*256 + threadIdx.x;   // 0 .. B*N/2-1
  size_t p0 = t*2;
  int b = (int)(p0 >> 17);
  int pinb = (int)(p0 & (size_t)(N_-1));             // even

  const float2* lp = (const float2*)(locs + p0*3);   // 24B, 8-aligned
  float2 a0=lp[0], a1=lp[1], a2=lp[2];
  float x0=a0.x*INV_R1, y0=a0.y*INV_R1, z0=a1.x*INV_R1;
  float x1=a1.y*INV_R1, y1=a2.x*INV_R1, z1=a2.y*INV_R1;

  float acc0[32], acc1[32];
  #pragma unroll
  for (int j=0;j<32;j++){
    float wa=wsw[OW1AS+j], wb=wsw[OW1AS+32+j], wc=wsw[OW1AS+64+j];
    acc0[j] = x0*wa + y0*wb + z0*wc;
    acc1[j] = x1*wa + y1*wb + z1*wc;
  }
  const float* fb = feats + (size_t)b*C_*N_ + pinb;
  #pragma unroll
  for (int c=0;c<32;c++){
    float2 f = *(const float2*)(fb + (size_t)c*N_);   // coalesced 8B/lane
    #pragma unroll
    for (int j=0;j<32;j++){
      float w = wsw[OW1AS + (6+c)*32 + j];            // wave-uniform -> s_load
      acc0[j] = fmaf(f.x, w, acc0[j]);
      acc1[j] = fmaf(f.y, w, acc1[j]);
    }
  }
  union U { float4 v[4]; __hip_bfloat16 h[32]; } r0, r1;
  #pragma unroll
  for (int j=0;j<32;j++){ r0.h[j]=__float2bfloat16(acc0[j]); r1.h[j]=__float2bfloat16(acc1[j]); }
  float4* dst = (float4*)(prec + p0*32);              // 128B/thread
  dst[0]=r0.v[0]; dst[1]=r0.v[1]; dst[2]=r0.v[2]; dst[3]=r0.v[3];
  dst[4]=r1.v[0]; dst[5]=r1.v[1]; dst[6]=r1.v[2]; dst[7]=r1.v[3];
}

// ---------------------------------------------------------------- k_centers
__global__ __launch_bounds__(256) void k_centers(
    const float* __restrict__ locs,
    const float* __restrict__ boxes,
    const int* __restrict__ fps_inds,
    const float* __restrict__ t1a,
    const float* __restrict__ wsw,
    float* __restrict__ ctr,
    float* __restrict__ out0,
    float* __restrict__ out2,
    float* __restrict__ out3)
{
  int i = blockIdx.x*256 + threadIdx.x;   // 0..8191
  int b = i >> 10;
  int idx = fps_inds[i];
  size_t src = (size_t)b*N_ + (uint32_t)idx;

  float x = locs[src*3+0], y = locs[src*3+1], z = locs[src*3+2];
  out0[(size_t)i*3+0]=x; out0[(size_t)i*3+1]=y; out0[(size_t)i*3+2]=z;
  float bx0=boxes[src*6+0], bx1=boxes[src*6+1], bx2=boxes[src*6+2];
  float bx3=boxes[src*6+3], bx4=boxes[src*6+4], bx5=boxes[src*6+5];
  out2[(size_t)i*6+0]=bx0; out2[(size_t)i*6+1]=bx1; out2[(size_t)i*6+2]=bx2;
  out2[(size_t)i*6+3]=bx3; out2[(size_t)i*6+4]=bx4; out2[(size_t)i*6+5]=bx5;
  out3[i] = (float)idx;

  float d0=bx3-bx0, d1=bx4-bx1, d2=bx5-bx2;
  float* cr = ctr + (size_t)i*104;
  cr[0]=x; cr[1]=y; cr[2]=z; cr[3]=d0; cr[4]=d1; cr[5]=d2; cr[6]=0.f; cr[7]=0.f;
  float xr=x*INV_R1, yr=y*INV_R1, zr=z*INV_R1;
  #pragma unroll
  for (int j=0;j<32;j++)
    cr[8+j] = t1a[j] - xr*wsw[OW1AS+j] - yr*wsw[OW1AS+32+j] - zr*wsw[OW1AS+64+j];
  float xq=x*INV_R2, yq=y*INV_R2, zq=z*INV_R2;
  #pragma unroll
  for (int j=0;j<64;j++)
    cr[40+j] = wsw[OT2+j] - xq*wsw[OW2S+j] - yq*wsw[OW2S+64+j] - zq*wsw[OW2S+128+j];
}

// ---------------------------------------------------------------- k_stage1
// One wave per (b,s); lane = neighbor. Layer2 32->64 scalar-weight FMAs; channel-max
// via FOLD reduction (126 shfls instead of 384): at step s keep upper/lower half of
// the channel array by (lane&s); lane ends holding channel==lane's max.
__global__ __launch_bounds__(256) void k_stage1(
    const float* __restrict__ boxes,
    const int* __restrict__ neighbor_inds,
    const __hip_bfloat16* __restrict__ prec,
    const float* __restrict__ wsw,
    const float* __restrict__ ctr,
    float* __restrict__ nf,
    float* __restrict__ p2)
{
  int wid  = (blockIdx.x*256 + threadIdx.x) >> 6;  // 0..8191 = b*S+s
  int lane = threadIdx.x & 63;
  int uwid = __builtin_amdgcn_readfirstlane(wid);
  int b = uwid >> 10;

  int nbr = neighbor_inds[(size_t)uwid*64 + lane];
  size_t gp = (size_t)b*N_ + (uint32_t)nbr;

  union U { float4 v[4]; uint16_t u[32]; } r;
  const float4* psrc = (const float4*)(prec + gp*32);
  r.v[0]=psrc[0]; r.v[1]=psrc[1]; r.v[2]=psrc[2]; r.v[3]=psrc[3];

  const float2* bp = (const float2*)(boxes + gp*6);
  float2 q0=bp[0], q1=bp[1], q2=bp[2];

  const float* cr = ctr + (size_t)uwid*104;        // uniform -> scalar loads
  float ad0=fabsf((q1.y-q0.x)-cr[3]);
  float ad1=fabsf((q2.x-q0.y)-cr[4]);
  float ad2=fabsf((q2.y-q1.x)-cr[5]);

  float h[32];
  #pragma unroll
  for (int i=0;i<32;i++){
    float p = bfu(r.u[i]);
    float v = p + cr[8+i] + ad0*wsw[OW1AS+96+i] + ad1*wsw[OW1AS+128+i] + ad2*wsw[OW1AS+160+i];
    h[i] = fmaxf(v, 0.f);
  }
  float acc[64];
  #pragma unroll
  for (int j=0;j<64;j++) acc[j] = wsw[OT1B+j];
  #pragma unroll
  for (int i=0;i<32;i++){
    #pragma unroll
    for (int j=0;j<64;j++)
      acc[j] = fmaf(h[i], wsw[OW1BS + i*64 + j], acc[j]);   // scalar weight operand
  }
  // fold-max across lanes (neighbors): after all steps, lane L holds max of channel L
  #pragma unroll
  for (int s=32;s>=1;s>>=1){
    bool up = (lane & s) != 0;
    #pragma unroll
    for (int i=0;i<s;i++){
      float lo = fmaxf(acc[i],   __shfl_xor(acc[i],   s));
      float hi = fmaxf(acc[s+i], __shfl_xor(acc[s+i], s));
      acc[i] = up ? hi : lo;
    }
  }
  float mine = fmaxf(acc[0], 0.f);                  // relu(max) == max(relu)
  nf[(size_t)uwid*64 + lane] = mine;

  // P2[s][lane] = (cxyz/R2)@W2[0:3] + nf[s]@W2[6:70]
  float pv = (cr[0]*INV_R2)*wsw[OW2S+lane]
           + (cr[1]*INV_R2)*wsw[OW2S+64+lane]
           + (cr[2]*INV_R2)*wsw[OW2S+128+lane];
  #pragma unroll
  for (int i=0;i<64;i++)
    pv = fmaf(__shfl(mine, i), wsw[OW2S + (6+i)*64 + lane], pv);
  p2[(size_t)uwid*64 + lane] = pv;
}

// ---------------------------------------------------------------- k_stage23
// One wave per 4 centers (G=4): weight vmem (W3a/W3b, 128KB/wave) amortized 4x,
// shfl broadcasts and weight loads each feed 4 centers. lane = channel.
__global__ __launch_bounds__(256) void k_stage23(
    const int* __restrict__ ninds2,
    const float* __restrict__ wsw,
    const float* __restrict__ ctr,
    const float* __restrict__ nf,
    const float* __restrict__ p2,
    float* __restrict__ hout)
{
  int wid  = (blockIdx.x*256 + threadIdx.x) >> 6;   // 0..2047
  int lane = threadIdx.x & 63;
  int uw = __builtin_amdgcn_readfirstlane(wid);
  int c0 = uw*4;                                    // first center (4 | 1024 so same batch)
  int bS = c0 & ~1023;

  float q2v[4], m[4], cd0[4], cd1[4], cd2[4];
  #pragma unroll
  for (int g=0;g<4;g++){
    const float* cr = ctr + (size_t)(c0+g)*104;
    q2v[g] = cr[40+lane];
    cd0[g]=cr[3]; cd1[g]=cr[4]; cd2[g]=cr[5];
    m[g] = -3.4e38f;
  }
  float w30 = wsw[OW2S+192+lane];
  float w31 = wsw[OW2S+256+lane];
  float w32 = wsw[OW2S+320+lane];

  #pragma unroll 4
  for (int k=0;k<64;k++){
    #pragma unroll
    for (int g=0;g<4;g++){
      int nb = ninds2[(size_t)(c0+g)*64 + k];       // uniform -> s_load
      int gg = bS + nb;
      const float* ncr = ctr + (size_t)gg*104;
      float a0 = fabsf(ncr[3]-cd0[g]);
      float a1 = fabsf(ncr[4]-cd1[g]);
      float a2 = fabsf(ncr[5]-cd2[g]);
      float v = p2[(size_t)gg*64 + lane] + q2v[g] + a0*w30 + a1*w31 + a2*w32;
      m[g] = fmaxf(m[g], v);
    }
  }

  // MLP3 layer 1: h3[g][t] for channel t*64+lane
  float h3[4][4];
  #pragma unroll
  for (int g=0;g<4;g++)
    #pragma unroll
    for (int t=0;t<4;t++) h3[g][t] = wsw[OT3A + t*64 + lane];
  #pragma unroll 8
  for (int i=0;i<64;i++){
    float wv0 = wsw[OW3AS + i*256 +   0 + lane];
    float wv1 = wsw[OW3AS + i*256 +  64 + lane];
    float wv2 = wsw[OW3AS + i*256 + 128 + lane];
    float wv3 = wsw[OW3AS + i*256 + 192 + lane];
    #pragma unroll
    for (int g=0;g<4;g++){
      float h2i = __shfl(m[g], i);
      h3[g][0] = fmaf(h2i, wv0, h3[g][0]);
      h3[g][1] = fmaf(h2i, wv1, h3[g][1]);
      h3[g][2] = fmaf(h2i, wv2, h3[g][2]);
      h3[g][3] = fmaf(h2i, wv3, h3[g][3]);
    }
  }
  #pragma unroll
  for (int g=0;g<4;g++)
    #pragma unroll
    for (int t=0;t<4;t++) h3[g][t] = fmaxf(h3[g][t], 0.f);

  // layer 2: o[g][lane] = t3b + sum_i relu(h3)[i] * W3b[i][lane]
  float o[4];
  #pragma unroll
  for (int g=0;g<4;g++) o[g] = wsw[OT3B + lane];
  #pragma unroll
  for (int t=0;t<4;t++){
    #pragma unroll 8
    for (int l=0;l<64;l++){
      float wb = wsw[OW3BS + (t*64+l)*64 + lane];
      #pragma unroll
      for (int g=0;g<4;g++)
        o[g] = fmaf(__shfl(h3[g][t], l), wb, o[g]);
    }
  }
  #pragma unroll
  for (int g=0;g<4;g++){
    float idv = nf[(size_t)(c0+g)*64 + lane];
    hout[(size_t)(c0+g)*64 + lane] = fmaxf(o[g] + idv, 0.f);
  }
}

// ---------------------------------------------------------------- k_transpose
__global__ __launch_bounds__(256) void k_transpose(
    const float* __restrict__ hout, float* __restrict__ out1)
{
  __shared__ float tile[64][65];
  int bb = blockIdx.x >> 4;
  int s0 = (blockIdx.x & 15) << 6;
  int c  = threadIdx.x & 63;
  int r4 = threadIdx.x >> 6;      // 0..3
  #pragma unroll
  for (int r=0;r<16;r++){
    int sr = r*4 + r4;
    tile[sr][c] = hout[((size_t)bb*S_ + s0 + sr)*64 + c];
  }
  __syncthreads();
  #pragma unroll
  for (int r=0;r<16;r++){
    int j = r*4 + r4;
    out1[(size_t)bb*64*S_ + (size_t)j*S_ + s0 + c] = tile[c][j];
  }
}

// ---------------------------------------------------------------- launch
extern "C" void kernel_launch(void* const* d_in, const int* in_sizes, int n_in,
                              void* d_out, int out_size, void* d_ws, size_t ws_size,
                              hipStream_t stream) {
  const float* locs  = (const float*)d_in[0];
  const float* feats = (const float*)d_in[1];
  const float* boxes = (const float*)d_in[2];
  const int* fps_inds = (const int*)d_in[3];
  const int* ninds    = (const int*)d_in[4];
  const int* ninds2   = (const int*)d_in[5];
  const float* w1a=(const float*)d_in[6];
  const float* s1a=(const float*)d_in[7];
  const float* t1a=(const float*)d_in[8];
  const float* w1b=(const float*)d_in[9];
  const float* s1b=(const float*)d_in[10];
  const float* t1b=(const float*)d_in[11];
  const float* w2 =(const float*)d_in[12];
  const float* s2 =(const float*)d_in[13];
  const float* t2 =(const float*)d_in[14];
  const float* w3a=(const float*)d_in[15];
  const float* s3a=(const float*)d_in[16];
  const float* t3a=(const float*)d_in[17];
  const float* w3b=(const float*)d_in[18];
  const float* s3b=(const float*)d_in[19];
  const float* t3b=(const float*)d_in[20];

  float* wsw  = (float*)d_ws;
  float* ctr  = (float*)((char*)d_ws + WS_CTR);
  float* nf   = (float*)((char*)d_ws + WS_NF);
  float* p2b  = (float*)((char*)d_ws + WS_P2);
  float* hout = (float*)((char*)d_ws + WS_HOUT);
  __hip_bfloat16* prec = (__hip_bfloat16*)((char*)d_ws + WS_PREC);

  float* out  = (float*)d_out;
  float* out0 = out;              // fps_locs  [B,S,3]
  float* out1 = out + 24576;      // features  [B,64,S]
  float* out2 = out + 548864;     // fps_boxes [B,S,6]
  float* out3 = out + 598016;     // fps_inds  [B,S]

  k_weights<<<160, 256, 0, stream>>>(w1a,s1a,w1b,s1b,t1b,w2,s2,t2,w3a,s3a,t3a,w3b,s3b,t3b,wsw);
  k_points<<<2048, 256, 0, stream>>>(locs, feats, wsw, prec);
  k_centers<<<32, 256, 0, stream>>>(locs, boxes, fps_inds, t1a, wsw, ctr, out0, out2, out3);
  k_stage1<<<2048, 256, 0, stream>>>(boxes, ninds, prec, wsw, ctr, nf, p2b);
  k_stage23<<<512, 256, 0, stream>>>(ninds2, wsw, ctr, nf, p2b, hout);
  k_transpose<<<128, 256, 0, stream>>>(hout, out1);
}

// Round 5
// 401.345 us; speedup vs baseline: 2.1596x; 2.1596x over previous
//
#include <hip/hip_runtime.h>
#include <hip/hip_bf16.h>
#include <stdint.h>

#define DEV __device__ __forceinline__

// Problem constants
constexpr int B_ = 8, N_ = 131072, S_ = 1024, C_ = 32;
constexpr float INV_R1 = 2.5f;   // 1/RADIUS (0.4)
constexpr float INV_R2 = 1.25f;  // 1/RADIUS_POST (0.8)

// Scaled-weight region offsets (in floats) inside ws
constexpr int OW1AS = 0;        // w1a*s1a      [38][32]
constexpr int OW1BS = 1216;     // w1b*s1b      [32][64]
constexpr int OT1B  = 3264;     // t1b          [64]
constexpr int OW2S  = 3328;     // w2*s2        [70][64]
constexpr int OT2   = 7808;     // t2           [64]
constexpr int OW3AS = 7872;     // w3a*s3a      [64][256]
constexpr int OT3A  = 24256;    // t3a          [256]
constexpr int OW3BS = 24512;    // w3b*s3b     [256][64]
constexpr int OT3B  = 40896;    // t3b          [64]   -> 40960 floats total

// ws byte offsets
constexpr size_t WS_CTR  = 163840;                          // ctr records [8192][104] f32
constexpr size_t WS_NF   = WS_CTR  + (size_t)8192*104*4;    // new_features [8192][64] f32
constexpr size_t WS_P2   = WS_NF   + (size_t)524288*4;      // stage2 point-precompute [8192][64] f32
constexpr size_t WS_HOUT = WS_P2   + (size_t)524288*4;      // final features [8192][64] f32
constexpr size_t WS_PREC = WS_HOUT + (size_t)524288*4;      // point records P [B*N][32] bf16

DEV float bfu(uint16_t u){ return __uint_as_float(((uint32_t)u) << 16); }

// ---------------------------------------------------------------- k_weights
__global__ void k_weights(
    const float* __restrict__ w1a, const float* __restrict__ s1a,
    const float* __restrict__ w1b, const float* __restrict__ s1b,
    const float* __restrict__ t1b,
    const float* __restrict__ w2,  const float* __restrict__ s2,
    const float* __restrict__ t2,
    const float* __restrict__ w3a, const float* __restrict__ s3a,
    const float* __restrict__ t3a,
    const float* __restrict__ w3b, const float* __restrict__ s3b,
    const float* __restrict__ t3b,
    float* __restrict__ wsw)
{
  int t = blockIdx.x*256 + threadIdx.x;
  int nth = gridDim.x*256;
  for (int i=t;i<38*32;i+=nth)  wsw[OW1AS+i] = w1a[i]*s1a[i&31];
  for (int i=t;i<32*64;i+=nth)  wsw[OW1BS+i] = w1b[i]*s1b[i&63];
  for (int i=t;i<64;i+=nth)     wsw[OT1B+i]  = t1b[i];
  for (int i=t;i<70*64;i+=nth)  wsw[OW2S+i]  = w2[i]*s2[i&63];
  for (int i=t;i<64;i+=nth)     wsw[OT2+i]   = t2[i];
  for (int i=t;i<64*256;i+=nth) wsw[OW3AS+i] = w3a[i]*s3a[i&255];
  for (int i=t;i<256;i+=nth)    wsw[OT3A+i]  = t3a[i];
  for (int i=t;i<256*64;i+=nth) wsw[OW3BS+i] = w3b[i]*s3b[i&63];
  for (int i=t;i<64;i+=nth)     wsw[OT3B+i]  = t3b[i];
}

// ---------------------------------------------------------------- k_points
// P[n] = (xyz/R)@W1a[0:3] + feats[n]@W1a[6:38], stored bf16. One point/thread
// (lane-stride-64B stores merge in L2 — 2pt/thread amplified WRITE 3.4x, r4).
// 8-deep double-buffered feats prefetch to cover vmem latency (r3 was 2-deep).
__global__ __launch_bounds__(256) void k_points(
    const float* __restrict__ locs,
    const float* __restrict__ feats,
    const float* __restrict__ wsw,
    __hip_bfloat16* __restrict__ prec)
{
  size_t p = (size_t)blockIdx.x*256 + threadIdx.x;   // 0 .. B*N-1
  int b = (int)(p >> 17);
  int pinb = (int)(p & (size_t)(N_-1));

  float x = locs[p*3+0]*INV_R1;
  float y = locs[p*3+1]*INV_R1;
  float z = locs[p*3+2]*INV_R1;

  float acc[32];
  #pragma unroll
  for (int j=0;j<32;j++)
    acc[j] = x*wsw[OW1AS+j] + y*wsw[OW1AS+32+j] + z*wsw[OW1AS+64+j];

  const float* fb = feats + (size_t)b*C_*N_ + pinb;
  float fcur[8], fnxt[8];
  #pragma unroll
  for (int i=0;i<8;i++) fcur[i] = fb[(size_t)i*N_];   // 8 outstanding loads
  #pragma unroll
  for (int ch=0;ch<4;ch++){
    if (ch<3){
      #pragma unroll
      for (int i=0;i<8;i++) fnxt[i] = fb[(size_t)(8*(ch+1)+i)*N_];
    }
    #pragma unroll
    for (int i=0;i<8;i++){
      int c = 8*ch+i;
      #pragma unroll
      for (int j=0;j<32;j++)
        acc[j] = fmaf(fcur[i], wsw[OW1AS + (6+c)*32 + j], acc[j]);  // s_load weights
    }
    #pragma unroll
    for (int i=0;i<8;i++) fcur[i] = fnxt[i];
  }
  union U { float4 v[4]; __hip_bfloat16 h[32]; } r;
  #pragma unroll
  for (int j=0;j<32;j++) r.h[j] = __float2bfloat16(acc[j]);
  float4* dst = (float4*)(prec + p*32);                // 64B/point
  dst[0]=r.v[0]; dst[1]=r.v[1]; dst[2]=r.v[2]; dst[3]=r.v[3];
}

// ---------------------------------------------------------------- k_centers
__global__ __launch_bounds__(256) void k_centers(
    const float* __restrict__ locs,
    const float* __restrict__ boxes,
    const int* __restrict__ fps_inds,
    const float* __restrict__ t1a,
    const float* __restrict__ wsw,
    float* __restrict__ ctr,
    float* __restrict__ out0,
    float* __restrict__ out2,
    float* __restrict__ out3)
{
  int i = blockIdx.x*256 + threadIdx.x;   // 0..8191
  int b = i >> 10;
  int idx = fps_inds[i];
  size_t src = (size_t)b*N_ + (uint32_t)idx;

  float x = locs[src*3+0], y = locs[src*3+1], z = locs[src*3+2];
  out0[(size_t)i*3+0]=x; out0[(size_t)i*3+1]=y; out0[(size_t)i*3+2]=z;
  float bx0=boxes[src*6+0], bx1=boxes[src*6+1], bx2=boxes[src*6+2];
  float bx3=boxes[src*6+3], bx4=boxes[src*6+4], bx5=boxes[src*6+5];
  out2[(size_t)i*6+0]=bx0; out2[(size_t)i*6+1]=bx1; out2[(size_t)i*6+2]=bx2;
  out2[(size_t)i*6+3]=bx3; out2[(size_t)i*6+4]=bx4; out2[(size_t)i*6+5]=bx5;
  out3[i] = (float)idx;

  float d0=bx3-bx0, d1=bx4-bx1, d2=bx5-bx2;
  float* cr = ctr + (size_t)i*104;
  cr[0]=x; cr[1]=y; cr[2]=z; cr[3]=d0; cr[4]=d1; cr[5]=d2; cr[6]=0.f; cr[7]=0.f;
  float xr=x*INV_R1, yr=y*INV_R1, zr=z*INV_R1;
  #pragma unroll
  for (int j=0;j<32;j++)
    cr[8+j] = t1a[j] - xr*wsw[OW1AS+j] - yr*wsw[OW1AS+32+j] - zr*wsw[OW1AS+64+j];
  float xq=x*INV_R2, yq=y*INV_R2, zq=z*INV_R2;
  #pragma unroll
  for (int j=0;j<64;j++)
    cr[40+j] = wsw[OT2+j] - xq*wsw[OW2S+j] - yq*wsw[OW2S+64+j] - zq*wsw[OW2S+128+j];
}

// ---------------------------------------------------------------- k_stage1
// One wave per (b,s); lane = neighbor. Layer2 32->64 scalar-weight FMAs; channel-max
// via FOLD reduction (126 shfls): lane L ends holding channel L's max.
__global__ __launch_bounds__(256) void k_stage1(
    const float* __restrict__ boxes,
    const int* __restrict__ neighbor_inds,
    const __hip_bfloat16* __restrict__ prec,
    const float* __restrict__ wsw,
    const float* __restrict__ ctr,
    float* __restrict__ nf,
    float* __restrict__ p2)
{
  int wid  = (blockIdx.x*256 + threadIdx.x) >> 6;  // 0..8191 = b*S+s
  int lane = threadIdx.x & 63;
  int uwid = __builtin_amdgcn_readfirstlane(wid);
  int b = uwid >> 10;

  int nbr = neighbor_inds[(size_t)uwid*64 + lane];
  size_t gp = (size_t)b*N_ + (uint32_t)nbr;

  union U { float4 v[4]; uint16_t u[32]; } r;
  const float4* psrc = (const float4*)(prec + gp*32);
  r.v[0]=psrc[0]; r.v[1]=psrc[1]; r.v[2]=psrc[2]; r.v[3]=psrc[3];

  const float2* bp = (const float2*)(boxes + gp*6);
  float2 q0=bp[0], q1=bp[1], q2=bp[2];

  const float* cr = ctr + (size_t)uwid*104;        // uniform -> scalar loads
  float ad0=fabsf((q1.y-q0.x)-cr[3]);
  float ad1=fabsf((q2.x-q0.y)-cr[4]);
  float ad2=fabsf((q2.y-q1.x)-cr[5]);

  float h[32];
  #pragma unroll
  for (int i=0;i<32;i++){
    float p = bfu(r.u[i]);
    float v = p + cr[8+i] + ad0*wsw[OW1AS+96+i] + ad1*wsw[OW1AS+128+i] + ad2*wsw[OW1AS+160+i];
    h[i] = fmaxf(v, 0.f);
  }
  float acc[64];
  #pragma unroll
  for (int j=0;j<64;j++) acc[j] = wsw[OT1B+j];
  #pragma unroll
  for (int i=0;i<32;i++){
    #pragma unroll
    for (int j=0;j<64;j++)
      acc[j] = fmaf(h[i], wsw[OW1BS + i*64 + j], acc[j]);   // scalar weight operand
  }
  // fold-max across lanes (neighbors): after all steps, lane L holds max of channel L
  #pragma unroll
  for (int s=32;s>=1;s>>=1){
    bool up = (lane & s) != 0;
    #pragma unroll
    for (int i=0;i<s;i++){
      float lo = fmaxf(acc[i],   __shfl_xor(acc[i],   s));
      float hi = fmaxf(acc[s+i], __shfl_xor(acc[s+i], s));
      acc[i] = up ? hi : lo;
    }
  }
  float mine = fmaxf(acc[0], 0.f);                  // relu(max) == max(relu)
  nf[(size_t)uwid*64 + lane] = mine;

  // P2[s][lane] = (cxyz/R2)@W2[0:3] + nf[s]@W2[6:70]
  float pv = (cr[0]*INV_R2)*wsw[OW2S+lane]
           + (cr[1]*INV_R2)*wsw[OW2S+64+lane]
           + (cr[2]*INV_R2)*wsw[OW2S+128+lane];
  #pragma unroll
  for (int i=0;i<64;i++)
    pv = fmaf(__shfl(mine, i), wsw[OW2S + (6+i)*64 + lane], pv);
  p2[(size_t)uwid*64 + lane] = pv;
}

// ---------------------------------------------------------------- k_stage23
// One wave per 4 centers (G=4): weight traffic amortized 4x. lane = channel.
__global__ __launch_bounds__(256) void k_stage23(
    const int* __restrict__ ninds2,
    const float* __restrict__ wsw,
    const float* __restrict__ ctr,
    const float* __restrict__ nf,
    const float* __restrict__ p2,
    float* __restrict__ hout)
{
  int wid  = (blockIdx.x*256 + threadIdx.x) >> 6;   // 0..2047
  int lane = threadIdx.x & 63;
  int uw = __builtin_amdgcn_readfirstlane(wid);
  int c0 = uw*4;                                    // first center (same batch: 4 | 1024)
  int bS = c0 & ~1023;

  float q2v[4], m[4], cd0[4], cd1[4], cd2[4];
  #pragma unroll
  for (int g=0;g<4;g++){
    const float* cr = ctr + (size_t)(c0+g)*104;
    q2v[g] = cr[40+lane];
    cd0[g]=cr[3]; cd1[g]=cr[4]; cd2[g]=cr[5];
    m[g] = -3.4e38f;
  }
  float w30 = wsw[OW2S+192+lane];
  float w31 = wsw[OW2S+256+lane];
  float w32 = wsw[OW2S+320+lane];

  #pragma unroll 4
  for (int k=0;k<64;k++){
    #pragma unroll
    for (int g=0;g<4;g++){
      int nb = ninds2[(size_t)(c0+g)*64 + k];       // uniform -> s_load
      int gg = bS + nb;
      const float* ncr = ctr + (size_t)gg*104;
      float a0 = fabsf(ncr[3]-cd0[g]);
      float a1 = fabsf(ncr[4]-cd1[g]);
      float a2 = fabsf(ncr[5]-cd2[g]);
      float v = p2[(size_t)gg*64 + lane] + q2v[g] + a0*w30 + a1*w31 + a2*w32;
      m[g] = fmaxf(m[g], v);
    }
  }

  // MLP3 layer 1: h3[g][t] for channel t*64+lane
  float h3[4][4];
  #pragma unroll
  for (int g=0;g<4;g++)
    #pragma unroll
    for (int t=0;t<4;t++) h3[g][t] = wsw[OT3A + t*64 + lane];
  #pragma unroll 8
  for (int i=0;i<64;i++){
    float wv0 = wsw[OW3AS + i*256 +   0 + lane];
    float wv1 = wsw[OW3AS + i*256 +  64 + lane];
    float wv2 = wsw[OW3AS + i*256 + 128 + lane];
    float wv3 = wsw[OW3AS + i*256 + 192 + lane];
    #pragma unroll
    for (int g=0;g<4;g++){
      float h2i = __shfl(m[g], i);
      h3[g][0] = fmaf(h2i, wv0, h3[g][0]);
      h3[g][1] = fmaf(h2i, wv1, h3[g][1]);
      h3[g][2] = fmaf(h2i, wv2, h3[g][2]);
      h3[g][3] = fmaf(h2i, wv3, h3[g][3]);
    }
  }
  #pragma unroll
  for (int g=0;g<4;g++)
    #pragma unroll
    for (int t=0;t<4;t++) h3[g][t] = fmaxf(h3[g][t], 0.f);

  // layer 2: o[g][lane] = t3b + sum_i relu(h3)[i] * W3b[i][lane]
  float o[4];
  #pragma unroll
  for (int g=0;g<4;g++) o[g] = wsw[OT3B + lane];
  #pragma unroll
  for (int t=0;t<4;t++){
    #pragma unroll 8
    for (int l=0;l<64;l++){
      float wb = wsw[OW3BS + (t*64+l)*64 + lane];
      #pragma unroll
      for (int g=0;g<4;g++)
        o[g] = fmaf(__shfl(h3[g][t], l), wb, o[g]);
    }
  }
  #pragma unroll
  for (int g=0;g<4;g++){
    float idv = nf[(size_t)(c0+g)*64 + lane];
    hout[(size_t)(c0+g)*64 + lane] = fmaxf(o[g] + idv, 0.f);
  }
}

// ---------------------------------------------------------------- k_transpose
__global__ __launch_bounds__(256) void k_transpose(
    const float* __restrict__ hout, float* __restrict__ out1)
{
  __shared__ float tile[64][65];
  int bb = blockIdx.x >> 4;
  int s0 = (blockIdx.x & 15) << 6;
  int c  = threadIdx.x & 63;
  int r4 = threadIdx.x >> 6;      // 0..3
  #pragma unroll
  for (int r=0;r<16;r++){
    int sr = r*4 + r4;
    tile[sr][c] = hout[((size_t)bb*S_ + s0 + sr)*64 + c];
  }
  __syncthreads();
  #pragma unroll
  for (int r=0;r<16;r++){
    int j = r*4 + r4;
    out1[(size_t)bb*64*S_ + (size_t)j*S_ + s0 + c] = tile[c][j];
  }
}

// ---------------------------------------------------------------- launch
extern "C" void kernel_launch(void* const* d_in, const int* in_sizes, int n_in,
                              void* d_out, int out_size, void* d_ws, size_t ws_size,
                              hipStream_t stream) {
  const float* locs  = (const float*)d_in[0];
  const float* feats = (const float*)d_in[1];
  const float* boxes = (const float*)d_in[2];
  const int* fps_inds = (const int*)d_in[3];
  const int* ninds    = (const int*)d_in[4];
  const int* ninds2   = (const int*)d_in[5];
  const float* w1a=(const float*)d_in[6];
  const float* s1a=(const float*)d_in[7];
  const float* t1a=(const float*)d_in[8];
  const float* w1b=(const float*)d_in[9];
  const float* s1b=(const float*)d_in[10];
  const float* t1b=(const float*)d_in[11];
  const float* w2 =(const float*)d_in[12];
  const float* s2 =(const float*)d_in[13];
  const float* t2 =(const float*)d_in[14];
  const float* w3a=(const float*)d_in[15];
  const float* s3a=(const float*)d_in[16];
  const float* t3a=(const float*)d_in[17];
  const float* w3b=(const float*)d_in[18];
  const float* s3b=(const float*)d_in[19];
  const float* t3b=(const float*)d_in[20];

  float* wsw  = (float*)d_ws;
  float* ctr  = (float*)((char*)d_ws + WS_CTR);
  float* nf   = (float*)((char*)d_ws + WS_NF);
  float* p2b  = (float*)((char*)d_ws + WS_P2);
  float* hout = (float*)((char*)d_ws + WS_HOUT);
  __hip_bfloat16* prec = (__hip_bfloat16*)((char*)d_ws + WS_PREC);

  float* out  = (float*)d_out;
  float* out0 = out;              // fps_locs  [B,S,3]
  float* out1 = out + 24576;      // features  [B,64,S]
  float* out2 = out + 548864;     // fps_boxes [B,S,6]
  float* out3 = out + 598016;     // fps_inds  [B,S]

  k_weights<<<160, 256, 0, stream>>>(w1a,s1a,w1b,s1b,t1b,w2,s2,t2,w3a,s3a,t3a,w3b,s3b,t3b,wsw);
  k_points<<<4096, 256, 0, stream>>>(locs, feats, wsw, prec);
  k_centers<<<32, 256, 0, stream>>>(locs, boxes, fps_inds, t1a, wsw, ctr, out0, out2, out3);
  k_stage1<<<2048, 256, 0, stream>>>(boxes, ninds, prec, wsw, ctr, nf, p2b);
  k_stage23<<<512, 256, 0, stream>>>(ninds2, wsw, ctr, nf, p2b, hout);
  k_transpose<<<128, 256, 0, stream>>>(hout, out1);
}